// Round 1
// baseline (1391.783 us; speedup 1.0000x reference)
//
#include <hip/hip_runtime.h>

#define B_  16
#define S_  256
#define G_  2048
#define D_  512
#define H_  8
#define DK_ 64
#define E_  8

// ---------------------------------------------------------------------------
// Generic fp32 GEMM (NN): C[64x64 tile] = alpha * A(MxK,row) @ B(KxN,row)
// 256 threads, 4x4 per thread, k-chunk 32, A staged transposed in LDS.
// Batch z: aOff=(z/zdiv)*sAo+(z%zdiv)*sAi, bOff=(z/zdiv)*sBo+(z%zdiv)*sBi,
//          cOff=z*sC
// ---------------------------------------------------------------------------
__global__ void __launch_bounds__(256) gemm_nn(
    const float* __restrict__ A, const float* __restrict__ Bm, float* __restrict__ C,
    int K, int lda, int ldb, int ldc,
    long sAo, long sAi, long sBo, long sBi, long sC, int zdiv, float alpha)
{
    __shared__ float Ast[32][68];   // [k][m], rows 16B-aligned (68*4=272)
    __shared__ float Bs[32][68];    // [k][n]
    const int tid = threadIdx.x;
    const int tx = tid & 15, ty = tid >> 4;
    const int z = blockIdx.z;
    const float* Ab = A + (long)(z / zdiv) * sAo + (long)(z % zdiv) * sAi
                        + (long)blockIdx.y * 64 * lda;
    const float* Bb = Bm + (long)(z / zdiv) * sBo + (long)(z % zdiv) * sBi
                         + (long)blockIdx.x * 64;
    float* Cb = C + (long)z * sC + (long)blockIdx.y * 64 * ldc + (long)blockIdx.x * 64;

    float acc[4][4] = {};
    for (int k0 = 0; k0 < K; k0 += 32) {
#pragma unroll
        for (int p = 0; p < 2; ++p) {           // A tile 64x32, transpose into LDS
            int f = tid + p * 256;
            int row = f >> 3, k4 = f & 7;
            float4 v = *(const float4*)(Ab + (long)row * lda + k0 + 4 * k4);
            Ast[4*k4+0][row] = v.x; Ast[4*k4+1][row] = v.y;
            Ast[4*k4+2][row] = v.z; Ast[4*k4+3][row] = v.w;
        }
#pragma unroll
        for (int p = 0; p < 2; ++p) {           // B tile 32x64, direct
            int f = tid + p * 256;
            int kk = f >> 4, n4 = f & 15;
            *(float4*)&Bs[kk][4*n4] = *(const float4*)(Bb + (long)(k0 + kk) * ldb + 4 * n4);
        }
        __syncthreads();
#pragma unroll
        for (int kk = 0; kk < 32; ++kk) {
            float4 av = *(const float4*)&Ast[kk][4*ty];
            float4 bv = *(const float4*)&Bs[kk][4*tx];
            float a[4] = {av.x, av.y, av.z, av.w};
            float b[4] = {bv.x, bv.y, bv.z, bv.w};
#pragma unroll
            for (int i = 0; i < 4; ++i)
#pragma unroll
                for (int j = 0; j < 4; ++j) acc[i][j] += a[i] * b[j];
        }
        __syncthreads();
    }
#pragma unroll
    for (int i = 0; i < 4; ++i) {
        float4 v = make_float4(acc[i][0]*alpha, acc[i][1]*alpha,
                               acc[i][2]*alpha, acc[i][3]*alpha);
        *(float4*)(Cb + (long)(4*ty + i) * ldc + 4*tx) = v;
    }
}

// ---------------------------------------------------------------------------
// Generic fp32 GEMM (NT): C = alpha * A(MxK,row) @ B(NxK,row)^T
// ---------------------------------------------------------------------------
__global__ void __launch_bounds__(256) gemm_nt(
    const float* __restrict__ A, const float* __restrict__ Bm, float* __restrict__ C,
    int K, int lda, int ldb, int ldc,
    long sAo, long sBo, long sC, float alpha)
{
    __shared__ float Ast[32][68];
    __shared__ float Bst[32][68];   // [k][n] (B rows transposed in)
    const int tid = threadIdx.x;
    const int tx = tid & 15, ty = tid >> 4;
    const int z = blockIdx.z;
    const float* Ab = A + (long)z * sAo + (long)blockIdx.y * 64 * lda;
    const float* Bb = Bm + (long)z * sBo + (long)blockIdx.x * 64 * ldb;
    float* Cb = C + (long)z * sC + (long)blockIdx.y * 64 * ldc + (long)blockIdx.x * 64;

    float acc[4][4] = {};
    for (int k0 = 0; k0 < K; k0 += 32) {
#pragma unroll
        for (int p = 0; p < 2; ++p) {
            int f = tid + p * 256;
            int row = f >> 3, k4 = f & 7;
            float4 v = *(const float4*)(Ab + (long)row * lda + k0 + 4 * k4);
            Ast[4*k4+0][row] = v.x; Ast[4*k4+1][row] = v.y;
            Ast[4*k4+2][row] = v.z; Ast[4*k4+3][row] = v.w;
        }
#pragma unroll
        for (int p = 0; p < 2; ++p) {
            int f = tid + p * 256;
            int nrow = f >> 3, k4 = f & 7;
            float4 v = *(const float4*)(Bb + (long)nrow * ldb + k0 + 4 * k4);
            Bst[4*k4+0][nrow] = v.x; Bst[4*k4+1][nrow] = v.y;
            Bst[4*k4+2][nrow] = v.z; Bst[4*k4+3][nrow] = v.w;
        }
        __syncthreads();
#pragma unroll
        for (int kk = 0; kk < 32; ++kk) {
            float4 av = *(const float4*)&Ast[kk][4*ty];
            float4 bv = *(const float4*)&Bst[kk][4*tx];
            float a[4] = {av.x, av.y, av.z, av.w};
            float b[4] = {bv.x, bv.y, bv.z, bv.w};
#pragma unroll
            for (int i = 0; i < 4; ++i)
#pragma unroll
                for (int j = 0; j < 4; ++j) acc[i][j] += a[i] * b[j];
        }
        __syncthreads();
    }
#pragma unroll
    for (int i = 0; i < 4; ++i) {
        float4 v = make_float4(acc[i][0]*alpha, acc[i][1]*alpha,
                               acc[i][2]*alpha, acc[i][3]*alpha);
        *(float4*)(Cb + (long)(4*ty + i) * ldc + 4*tx) = v;
    }
}

// ---------------------------------------------------------------------------
// Flash attention per (b, h, 64-row s-tile). fp32, online softmax.
// KP buffer aliases K^T (during scores) and P (during PV) to stay <64KB LDS.
// ---------------------------------------------------------------------------
__global__ void __launch_bounds__(256) flash_attn(
    const float* __restrict__ Qp, const float* __restrict__ Kp,
    const float* __restrict__ Vp, const unsigned char* __restrict__ mask,
    float* __restrict__ Hd)
{
    __shared__ float Qst[64][68];   // Q^T: [k][s]
    __shared__ float KP[64][68];    // K^T: [k][g]  then  P: [s][g]
    __shared__ float Vs[64][68];    // V:   [g][k]
    const int tid = threadIdx.x;
    const int tx = tid & 15, ty = tid >> 4;
    const int tx4 = 4 * tx;
    const int s0 = blockIdx.x * 64;
    const int h = blockIdx.y, b = blockIdx.z;
    const long bh = (long)(b * H_ + h);
    const float* Qb = Qp + bh * (S_ * DK_) + (long)s0 * DK_;
    const float* Kb = Kp + bh * (G_ * DK_);
    const float* Vb = Vp + bh * (G_ * DK_);
    const unsigned char* mb = mask + (long)b * G_;

#pragma unroll
    for (int p = 0; p < 4; ++p) {               // stage Q once (64x64, transposed)
        int f = tid + p * 256;
        int row = f >> 4, k4 = f & 15;
        float4 v = *(const float4*)(Qb + (long)row * DK_ + 4 * k4);
        Qst[4*k4+0][row] = v.x; Qst[4*k4+1][row] = v.y;
        Qst[4*k4+2][row] = v.z; Qst[4*k4+3][row] = v.w;
    }

    float m[4], l[4] = {0.f, 0.f, 0.f, 0.f};
    float o[4][4] = {};
#pragma unroll
    for (int i = 0; i < 4; ++i) m[i] = -3.0e38f;

    for (int g0 = 0; g0 < G_; g0 += 64) {
#pragma unroll
        for (int p = 0; p < 4; ++p) {           // stage K (transposed) + V (direct)
            int f = tid + p * 256;
            int row = f >> 4, k4 = f & 15;
            float4 kv = *(const float4*)(Kb + (long)(g0 + row) * DK_ + 4 * k4);
            KP[4*k4+0][row] = kv.x; KP[4*k4+1][row] = kv.y;
            KP[4*k4+2][row] = kv.z; KP[4*k4+3][row] = kv.w;
            float4 vv = *(const float4*)(Vb + (long)(g0 + row) * DK_ + 4 * k4);
            *(float4*)&Vs[row][4*k4] = vv;
        }
        __syncthreads();

        float s[4][4] = {};                     // scores: rows 4ty+i, cols g0+4tx+j
#pragma unroll 8
        for (int kk = 0; kk < 64; ++kk) {
            float4 qv = *(const float4*)&Qst[kk][4*ty];
            float4 kv = *(const float4*)&KP[kk][tx4];
            float a[4] = {qv.x, qv.y, qv.z, qv.w};
            float bb[4] = {kv.x, kv.y, kv.z, kv.w};
#pragma unroll
            for (int i = 0; i < 4; ++i)
#pragma unroll
                for (int j = 0; j < 4; ++j) s[i][j] += a[i] * bb[j];
        }
        __syncthreads();                        // all K reads done before P writes

        unsigned int mw = *(const unsigned int*)(mb + g0 + tx4);
#pragma unroll
        for (int j = 0; j < 4; ++j) {
            bool mk = ((mw >> (8 * j)) & 0xffu) != 0u;
#pragma unroll
            for (int i = 0; i < 4; ++i) {
                float v = s[i][j] * 0.125f;     // 1/sqrt(DK)
                s[i][j] = mk ? -1.0e9f : v;
            }
        }
#pragma unroll
        for (int i = 0; i < 4; ++i) {
            float mt = fmaxf(fmaxf(s[i][0], s[i][1]), fmaxf(s[i][2], s[i][3]));
            mt = fmaxf(mt, __shfl_xor(mt, 1));
            mt = fmaxf(mt, __shfl_xor(mt, 2));
            mt = fmaxf(mt, __shfl_xor(mt, 4));
            mt = fmaxf(mt, __shfl_xor(mt, 8));  // 16-lane row group (same ty)
            float mn = fmaxf(m[i], mt);
            float al = __expf(m[i] - mn);       // first tile: exp(-3e38)=0
            float p0 = __expf(s[i][0] - mn), p1 = __expf(s[i][1] - mn);
            float p2 = __expf(s[i][2] - mn), p3 = __expf(s[i][3] - mn);
            float rs = p0 + p1 + p2 + p3;
            rs += __shfl_xor(rs, 1); rs += __shfl_xor(rs, 2);
            rs += __shfl_xor(rs, 4); rs += __shfl_xor(rs, 8);
            l[i] = l[i] * al + rs;
            m[i] = mn;
            o[i][0] *= al; o[i][1] *= al; o[i][2] *= al; o[i][3] *= al;
            *(float4*)&KP[4*ty + i][tx4] = make_float4(p0, p1, p2, p3);  // P
        }
        __syncthreads();                        // P visible

#pragma unroll 8
        for (int kk = 0; kk < 64; ++kk) {       // O += P @ V
            float4 vv = *(const float4*)&Vs[kk][tx4];
#pragma unroll
            for (int i = 0; i < 4; ++i) {
                float pi = KP[4*ty + i][kk];
                o[i][0] += pi * vv.x; o[i][1] += pi * vv.y;
                o[i][2] += pi * vv.z; o[i][3] += pi * vv.w;
            }
        }
        __syncthreads();                        // before next tile overwrites KP/Vs
    }
#pragma unroll
    for (int i = 0; i < 4; ++i) {
        float inv = 1.0f / l[i];
        float4 ov = make_float4(o[i][0]*inv, o[i][1]*inv, o[i][2]*inv, o[i][3]*inv);
        // heads layout [b][s][h*64+k] so Wo-merge is a plain GEMM vs Wo(512x512)
        *(float4*)(Hd + ((long)(b * S_ + s0 + 4*ty + i) * (H_ * DK_)) + h * DK_ + tx4) = ov;
    }
}

// ---------------------------------------------------------------------------
// Gate: logits = glimpse @ w_gate (4096x512 @ 512x8), top-2, softmax, dense gates
// One thread per token; x tile staged in LDS for coalescing.
// ---------------------------------------------------------------------------
__global__ void __launch_bounds__(256) gate_topk(
    const float* __restrict__ X, const float* __restrict__ wg, float* __restrict__ gates)
{
    __shared__ float W[512][8];     // 16KB, same layout as w_gate
    __shared__ float Xs[256][37];   // ld 37: conflict-free column reads
    const int tid = threadIdx.x;
    const int n0 = blockIdx.x * 256;
#pragma unroll
    for (int p = 0; p < 16; ++p) ((float*)W)[tid + p * 256] = wg[tid + p * 256];

    float acc[8] = {};
    for (int dc = 0; dc < 512; dc += 32) {
        __syncthreads();
#pragma unroll
        for (int p = 0; p < 8; ++p) {
            int f = tid + p * 256;
            int row = f >> 3, c4 = f & 7;
            float4 v = *(const float4*)(X + (long)(n0 + row) * 512 + dc + 4 * c4);
            Xs[row][4*c4+0] = v.x; Xs[row][4*c4+1] = v.y;
            Xs[row][4*c4+2] = v.z; Xs[row][4*c4+3] = v.w;
        }
        __syncthreads();
        for (int d2 = 0; d2 < 32; ++d2) {
            float xv = Xs[tid][d2];
#pragma unroll
            for (int e = 0; e < 8; ++e) acc[e] += xv * W[dc + d2][e];
        }
    }
    // top-2 (ties -> lower index, matching lax.top_k) + softmax over the pair
    float v1 = -3.0e38f; int i1 = 0;
#pragma unroll
    for (int e = 0; e < 8; ++e) if (acc[e] > v1) { v1 = acc[e]; i1 = e; }
    float v2 = -3.0e38f; int i2 = -1;
#pragma unroll
    for (int e = 0; e < 8; ++e) if (e != i1 && acc[e] > v2) { v2 = acc[e]; i2 = e; }
    float t = __expf(v2 - v1);
    float g1 = 1.0f / (1.0f + t);
    float g2 = t / (1.0f + t);
#pragma unroll
    for (int e = 0; e < 8; ++e)
        gates[(long)(n0 + tid) * 8 + e] = (e == i1) ? g1 : ((e == i2) ? g2 : 0.0f);
}

// ---------------------------------------------------------------------------
// MoE: gm[n,d] = sum_e gates[n,e] * (X @ Ew[e])[n,d]  (dense over 8 experts)
// ---------------------------------------------------------------------------
__global__ void __launch_bounds__(256) moe_gemm(
    const float* __restrict__ X, const float* __restrict__ Ew,
    const float* __restrict__ gates, float* __restrict__ Y)
{
    __shared__ float Ast[32][68];
    __shared__ float Bs[32][68];
    __shared__ float Gs[512];
    const int tid = threadIdx.x;
    const int tx = tid & 15, ty = tid >> 4;
    const int m0 = blockIdx.y * 64, n0 = blockIdx.x * 64;
    Gs[tid]       = gates[(long)m0 * 8 + tid];
    Gs[tid + 256] = gates[(long)m0 * 8 + 256 + tid];

    float acc[4][4] = {};
    for (int e = 0; e < E_; ++e) {
        const float* Eb = Ew + (long)e * 512 * 512 + n0;
        float pacc[4][4] = {};
        for (int k0 = 0; k0 < 512; k0 += 32) {
            __syncthreads();
#pragma unroll
            for (int p = 0; p < 2; ++p) {
                int f = tid + p * 256;
                int row = f >> 3, k4 = f & 7;
                float4 v = *(const float4*)(X + (long)(m0 + row) * 512 + k0 + 4 * k4);
                Ast[4*k4+0][row] = v.x; Ast[4*k4+1][row] = v.y;
                Ast[4*k4+2][row] = v.z; Ast[4*k4+3][row] = v.w;
            }
#pragma unroll
            for (int p = 0; p < 2; ++p) {
                int f = tid + p * 256;
                int kk = f >> 4, n4 = f & 15;
                *(float4*)&Bs[kk][4*n4] = *(const float4*)(Eb + (long)(k0 + kk) * 512 + 4 * n4);
            }
            __syncthreads();
#pragma unroll
            for (int kk = 0; kk < 32; ++kk) {
                float4 av = *(const float4*)&Ast[kk][4*ty];
                float4 bv = *(const float4*)&Bs[kk][4*tx];
                float a[4] = {av.x, av.y, av.z, av.w};
                float b[4] = {bv.x, bv.y, bv.z, bv.w};
#pragma unroll
                for (int i = 0; i < 4; ++i)
#pragma unroll
                    for (int j = 0; j < 4; ++j) pacc[i][j] += a[i] * b[j];
            }
        }
#pragma unroll
        for (int i = 0; i < 4; ++i) {
            float ge = Gs[(4*ty + i) * 8 + e];
#pragma unroll
            for (int j = 0; j < 4; ++j) acc[i][j] += ge * pacc[i][j];
        }
    }
#pragma unroll
    for (int i = 0; i < 4; ++i) {
        float4 v = make_float4(acc[i][0], acc[i][1], acc[i][2], acc[i][3]);
        *(float4*)(Y + (long)(m0 + 4*ty + i) * 512 + n0 + 4*tx) = v;
    }
}

// ---------------------------------------------------------------------------
extern "C" void kernel_launch(void* const* d_in, const int* in_sizes, int n_in,
                              void* d_out, int out_size, void* d_ws, size_t ws_size,
                              hipStream_t stream) {
    const float* query     = (const float*)d_in[0];
    const float* key       = (const float*)d_in[1];
    // d_in[2] = value: UNUSED by the reference (V is projected from `key`)
    const float* logit_key = (const float*)d_in[3];
    const unsigned char* mask = (const unsigned char*)d_in[4];
    const float* Wq = (const float*)d_in[5];
    const float* Wk = (const float*)d_in[6];
    const float* Wv = (const float*)d_in[7];
    const float* Wo = (const float*)d_in[8];
    const float* wg = (const float*)d_in[9];
    const float* Ew = (const float*)d_in[10];
    float* out = (float*)d_out;

    float* ws      = (float*)d_ws;
    float* Qp      = ws;                    // [B][H][S][DK]   2,097,152
    float* Kp      = Qp + 2097152;          // [B][H][G][DK]  16,777,216
    float* Vp      = Kp + 16777216;         // [B][H][G][DK]  16,777,216
    float* Hd      = Vp + 16777216;         // [B][S][H*DK]    2,097,152
    float* glimpse = Hd + 2097152;          // [B][S][D]       2,097,152
    float* gates   = glimpse + 2097152;     // [N][E]             32,768
    float* gm      = gates + 32768;         // [B][S][D]       2,097,152
    // total ~160.2 MB of d_ws

    dim3 blk(256);

    // Q = query @ Wq[h]  : per (b,h) 256x64, K=512
    gemm_nn<<<dim3(1, 4, 128), blk, 0, stream>>>(
        query, Wq, Qp, 512, 512, 64, 64,
        (long)S_ * D_, 0L, 0L, (long)D_ * DK_, (long)S_ * DK_, H_, 1.0f);
    // K = key @ Wk[h]    : per (b,h) 2048x64
    gemm_nn<<<dim3(1, 32, 128), blk, 0, stream>>>(
        key, Wk, Kp, 512, 512, 64, 64,
        (long)G_ * D_, 0L, 0L, (long)D_ * DK_, (long)G_ * DK_, H_, 1.0f);
    // V = key @ Wv[h]
    gemm_nn<<<dim3(1, 32, 128), blk, 0, stream>>>(
        key, Wv, Vp, 512, 512, 64, 64,
        (long)G_ * D_, 0L, 0L, (long)D_ * DK_, (long)G_ * DK_, H_, 1.0f);

    // flash attention -> Hd[b][s][h*64+k]
    flash_attn<<<dim3(4, H_, B_), blk, 0, stream>>>(Qp, Kp, Vp, mask, Hd);

    // glimpse = Hd @ Wo2d (512x512); per b 256x512
    gemm_nn<<<dim3(8, 4, 16), blk, 0, stream>>>(
        Hd, Wo, glimpse, 512, 512, 512, 512,
        (long)S_ * D_, 0L, 0L, 0L, (long)S_ * D_, 1, 1.0f);

    // gating: logits, top-2, softmax -> dense gates
    gate_topk<<<dim3(16), blk, 0, stream>>>(glimpse, wg, gates);

    // MoE: gm = sum_e gates[:,e] * (glimpse @ Ew[e])
    moe_gemm<<<dim3(8, 64), blk, 0, stream>>>(glimpse, Ew, gates, gm);

    // out[b,s,g] = gm[b] @ logit_key[b]^T / sqrt(512); per b 256x2048, K=512
    gemm_nt<<<dim3(32, 4, 16), blk, 0, stream>>>(
        gm, logit_key, out, 512, 512, 512, 2048,
        (long)S_ * D_, (long)G_ * D_, (long)S_ * G_, 0.04419417382415922f);
}

// Round 2
// 831.738 us; speedup vs baseline: 1.6733x; 1.6733x over previous
//
#include <hip/hip_runtime.h>

#define B_  16
#define S_  256
#define G_  2048
#define D_  512
#define H_  8
#define DK_ 64
#define E_  8

typedef _Float16 half8  __attribute__((ext_vector_type(8)));
typedef _Float16 half4v __attribute__((ext_vector_type(4)));
typedef float    floatx4 __attribute__((ext_vector_type(4)));

// async global->LDS, 16B per lane; LDS dest = wave-uniform base + lane*16
#define GLDS(g, l) __builtin_amdgcn_global_load_lds( \
    (const __attribute__((address_space(1))) void*)(g), \
    (__attribute__((address_space(3))) void*)(l), 16, 0, 0)

// ---------------------------------------------------------------------------
// split fp32 -> hi/lo f16 (x = hi + lo exactly to ~2^-22 rel)
// ---------------------------------------------------------------------------
__global__ void __launch_bounds__(256) split_f16(
    const float* __restrict__ src, _Float16* __restrict__ hi,
    _Float16* __restrict__ lo, int n4)
{
    int i = blockIdx.x * 256 + threadIdx.x;
    if (i >= n4) return;
    float4 v = ((const float4*)src)[i];
    half4v h, l;
    h[0] = (_Float16)v.x; h[1] = (_Float16)v.y;
    h[2] = (_Float16)v.z; h[3] = (_Float16)v.w;
    l[0] = (_Float16)(v.x - (float)h[0]); l[1] = (_Float16)(v.y - (float)h[1]);
    l[2] = (_Float16)(v.z - (float)h[2]); l[3] = (_Float16)(v.w - (float)h[3]);
    ((half4v*)hi)[i] = h;
    ((half4v*)lo)[i] = l;
}

// ---------------------------------------------------------------------------
// transpose + split: dst[c][r] = src[z][r][c], dst ld = R. (weights pack)
// grid: (C/32, R/32, Z)
// ---------------------------------------------------------------------------
__global__ void __launch_bounds__(256) transpose_split(
    const float* __restrict__ src, _Float16* __restrict__ hi,
    _Float16* __restrict__ lo, int R, int C)
{
    __shared__ float T[32][33];
    const int tid = threadIdx.x;
    const long zo = (long)blockIdx.z * R * C;
    const int r0 = blockIdx.y * 32, c0 = blockIdx.x * 32;
#pragma unroll
    for (int p = 0; p < 4; ++p) {
        int i = tid + p * 256;
        int lr = i >> 5, lc = i & 31;
        T[lr][lc] = src[zo + (long)(r0 + lr) * C + (c0 + lc)];
    }
    __syncthreads();
#pragma unroll
    for (int p = 0; p < 4; ++p) {
        int i = tid + p * 256;
        int orr = i >> 5, oc = i & 31;
        float v = T[oc][orr];
        _Float16 h = (_Float16)v;
        long o = zo + (long)(c0 + orr) * R + (r0 + oc);
        hi[o] = h;
        lo[o] = (_Float16)(v - (float)h);
    }
}

// ---------------------------------------------------------------------------
// f16x3 MFMA GEMM (NT): C = alpha * (Ah+Al)(M x 512) @ (Bh+Bl)(N x 512)^T
// 128x128 tile, 4 waves (64x64 each, 4x4 of 16x16x32 MFMA), BK=32.
// A,B k-major ld=512. Optional split output (Chi/Clo non-null).
// z: A rows += z*sAz, B rows += z*sBz, C += z*sCz.
// ---------------------------------------------------------------------------
__global__ void __launch_bounds__(256) gemm_f16x3(
    const _Float16* __restrict__ Ah, const _Float16* __restrict__ Al,
    const _Float16* __restrict__ Bh, const _Float16* __restrict__ Bl,
    float* __restrict__ C, _Float16* __restrict__ Chi, _Float16* __restrict__ Clo,
    int ldc, long sAz, long sBz, long sCz, float alpha)
{
    __shared__ _Float16 Ash[128 * 32], Asl[128 * 32];
    __shared__ _Float16 Bsh[128 * 32], Bsl[128 * 32];
    const int tid = threadIdx.x;
    const int w = tid >> 6, lane = tid & 63;
    const int quad = lane >> 4, tn = lane & 15;
    const int wm = (w >> 1) * 64, wn = (w & 1) * 64;
    const int z = blockIdx.z;
    const long m0 = (long)blockIdx.y * 128;
    const long n0 = (long)blockIdx.x * 128;
    const _Float16* Agh = Ah + (z * sAz + m0) * 512;
    const _Float16* Agl = Al + (z * sAz + m0) * 512;
    const _Float16* Bgh = Bh + (z * sBz + n0) * 512;
    const _Float16* Bgl = Bl + (z * sBz + n0) * 512;
    const long glane = (long)(lane >> 2) * 512 + (lane & 3) * 8;

    floatx4 acc[4][4] = {};

    for (int k0 = 0; k0 < 512; k0 += 32) {
#pragma unroll
        for (int cc = 0; cc < 2; ++cc) {           // each wave stages 2 of 8 chunks
            const int c = 2 * w + cc;
            const long go = (long)c * 16 * 512 + glane + k0;
            GLDS(Agh + go, Ash + c * 512);
            GLDS(Agl + go, Asl + c * 512);
            GLDS(Bgh + go, Bsh + c * 512);
            GLDS(Bgl + go, Bsl + c * 512);
        }
        asm volatile("s_waitcnt vmcnt(0)" ::: "memory");
        __syncthreads();

        half8 ah[4], al[4], bh[4], bl[4];
#pragma unroll
        for (int t = 0; t < 4; ++t) {
            ah[t] = *(const half8*)&Ash[(wm + t * 16 + tn) * 32 + quad * 8];
            al[t] = *(const half8*)&Asl[(wm + t * 16 + tn) * 32 + quad * 8];
            bh[t] = *(const half8*)&Bsh[(wn + t * 16 + tn) * 32 + quad * 8];
            bl[t] = *(const half8*)&Bsl[(wn + t * 16 + tn) * 32 + quad * 8];
        }
#pragma unroll
        for (int i = 0; i < 4; ++i)
#pragma unroll
            for (int j = 0; j < 4; ++j) {
                acc[i][j] = __builtin_amdgcn_mfma_f32_16x16x32_f16(ah[i], bh[j], acc[i][j], 0, 0, 0);
                acc[i][j] = __builtin_amdgcn_mfma_f32_16x16x32_f16(ah[i], bl[j], acc[i][j], 0, 0, 0);
                acc[i][j] = __builtin_amdgcn_mfma_f32_16x16x32_f16(al[i], bh[j], acc[i][j], 0, 0, 0);
            }
        __syncthreads();
    }

    float* Cb = C + (long)z * sCz;
#pragma unroll
    for (int i = 0; i < 4; ++i) {
        const long row0 = m0 + wm + i * 16 + quad * 4;
#pragma unroll
        for (int r = 0; r < 4; ++r) {
            const long row = row0 + r;
#pragma unroll
            for (int j = 0; j < 4; ++j) {
                float v = acc[i][j][r] * alpha;
                const long o = row * ldc + n0 + wn + j * 16 + tn;
                Cb[o] = v;
                if (Chi) {
                    _Float16 h = (_Float16)v;
                    Chi[o] = h;
                    Clo[o] = (_Float16)(v - (float)h);
                }
            }
        }
    }
}

// ---------------------------------------------------------------------------
// Flash attention per (b, h, 64-row s-tile). fp32, online softmax.
// Q/K/V in concatenated layout [b][s|g][h*64+k], row stride 512.
// Epilogue writes hi/lo f16 heads for the Wo GEMM.
// ---------------------------------------------------------------------------
__global__ void __launch_bounds__(256) flash_attn(
    const float* __restrict__ Qp, const float* __restrict__ Kp,
    const float* __restrict__ Vp, const unsigned char* __restrict__ mask,
    _Float16* __restrict__ hd_hi, _Float16* __restrict__ hd_lo)
{
    __shared__ float Qst[64][68];   // Q^T: [k][s]
    __shared__ float KP[64][68];    // K^T: [k][g]  then  P: [s][g]
    __shared__ float Vs[64][68];    // V:   [g][k]
    const int tid = threadIdx.x;
    const int tx = tid & 15, ty = tid >> 4;
    const int tx4 = 4 * tx;
    const int s0 = blockIdx.x * 64;
    const int h = blockIdx.y, b = blockIdx.z;
    const float* Qb = Qp + ((long)b * S_ + s0) * 512 + h * 64;
    const float* Kb = Kp + (long)b * G_ * 512 + h * 64;
    const float* Vb = Vp + (long)b * G_ * 512 + h * 64;
    const unsigned char* mb = mask + (long)b * G_;

#pragma unroll
    for (int p = 0; p < 4; ++p) {               // stage Q once (64x64, transposed)
        int f = tid + p * 256;
        int row = f >> 4, k4 = f & 15;
        float4 v = *(const float4*)(Qb + (long)row * 512 + 4 * k4);
        Qst[4*k4+0][row] = v.x; Qst[4*k4+1][row] = v.y;
        Qst[4*k4+2][row] = v.z; Qst[4*k4+3][row] = v.w;
    }

    float m[4], l[4] = {0.f, 0.f, 0.f, 0.f};
    float o[4][4] = {};
#pragma unroll
    for (int i = 0; i < 4; ++i) m[i] = -3.0e38f;

    for (int g0 = 0; g0 < G_; g0 += 64) {
#pragma unroll
        for (int p = 0; p < 4; ++p) {           // stage K (transposed) + V (direct)
            int f = tid + p * 256;
            int row = f >> 4, k4 = f & 15;
            float4 kv = *(const float4*)(Kb + (long)(g0 + row) * 512 + 4 * k4);
            KP[4*k4+0][row] = kv.x; KP[4*k4+1][row] = kv.y;
            KP[4*k4+2][row] = kv.z; KP[4*k4+3][row] = kv.w;
            float4 vv = *(const float4*)(Vb + (long)(g0 + row) * 512 + 4 * k4);
            *(float4*)&Vs[row][4*k4] = vv;
        }
        __syncthreads();

        float s[4][4] = {};
#pragma unroll 8
        for (int kk = 0; kk < 64; ++kk) {
            float4 qv = *(const float4*)&Qst[kk][4*ty];
            float4 kv = *(const float4*)&KP[kk][tx4];
            float a[4] = {qv.x, qv.y, qv.z, qv.w};
            float bb[4] = {kv.x, kv.y, kv.z, kv.w};
#pragma unroll
            for (int i = 0; i < 4; ++i)
#pragma unroll
                for (int j = 0; j < 4; ++j) s[i][j] += a[i] * bb[j];
        }
        __syncthreads();                        // K reads done before P writes

        unsigned int mw = *(const unsigned int*)(mb + g0 + tx4);
#pragma unroll
        for (int j = 0; j < 4; ++j) {
            bool mk = ((mw >> (8 * j)) & 0xffu) != 0u;
#pragma unroll
            for (int i = 0; i < 4; ++i) {
                float v = s[i][j] * 0.125f;     // 1/sqrt(DK)
                s[i][j] = mk ? -1.0e9f : v;
            }
        }
#pragma unroll
        for (int i = 0; i < 4; ++i) {
            float mt = fmaxf(fmaxf(s[i][0], s[i][1]), fmaxf(s[i][2], s[i][3]));
            mt = fmaxf(mt, __shfl_xor(mt, 1));
            mt = fmaxf(mt, __shfl_xor(mt, 2));
            mt = fmaxf(mt, __shfl_xor(mt, 4));
            mt = fmaxf(mt, __shfl_xor(mt, 8));
            float mn = fmaxf(m[i], mt);
            float al = __expf(m[i] - mn);
            float p0 = __expf(s[i][0] - mn), p1 = __expf(s[i][1] - mn);
            float p2 = __expf(s[i][2] - mn), p3 = __expf(s[i][3] - mn);
            float rs = p0 + p1 + p2 + p3;
            rs += __shfl_xor(rs, 1); rs += __shfl_xor(rs, 2);
            rs += __shfl_xor(rs, 4); rs += __shfl_xor(rs, 8);
            l[i] = l[i] * al + rs;
            m[i] = mn;
            o[i][0] *= al; o[i][1] *= al; o[i][2] *= al; o[i][3] *= al;
            *(float4*)&KP[4*ty + i][tx4] = make_float4(p0, p1, p2, p3);
        }
        __syncthreads();

#pragma unroll 8
        for (int kk = 0; kk < 64; ++kk) {       // O += P @ V
            float4 vv = *(const float4*)&Vs[kk][tx4];
#pragma unroll
            for (int i = 0; i < 4; ++i) {
                float pi = KP[4*ty + i][kk];
                o[i][0] += pi * vv.x; o[i][1] += pi * vv.y;
                o[i][2] += pi * vv.z; o[i][3] += pi * vv.w;
            }
        }
        __syncthreads();
    }
#pragma unroll
    for (int i = 0; i < 4; ++i) {
        float inv = 1.0f / l[i];
        float ov[4] = {o[i][0]*inv, o[i][1]*inv, o[i][2]*inv, o[i][3]*inv};
        long base = ((long)(b * S_ + s0 + 4*ty + i)) * 512 + h * 64 + tx4;
        half4v hh, hl;
#pragma unroll
        for (int q = 0; q < 4; ++q) {
            hh[q] = (_Float16)ov[q];
            hl[q] = (_Float16)(ov[q] - (float)hh[q]);
        }
        *(half4v*)(hd_hi + base) = hh;
        *(half4v*)(hd_lo + base) = hl;
    }
}

// ---------------------------------------------------------------------------
// Gate: logits = glimpse @ w_gate, top-2, softmax -> dense gates (fp32)
// ---------------------------------------------------------------------------
__global__ void __launch_bounds__(256) gate_topk(
    const float* __restrict__ X, const float* __restrict__ wg, float* __restrict__ gates)
{
    __shared__ float W[512][8];
    __shared__ float Xs[256][37];
    const int tid = threadIdx.x;
    const int n0 = blockIdx.x * 256;
#pragma unroll
    for (int p = 0; p < 16; ++p) ((float*)W)[tid + p * 256] = wg[tid + p * 256];

    float acc[8] = {};
    for (int dc = 0; dc < 512; dc += 32) {
        __syncthreads();
#pragma unroll
        for (int p = 0; p < 8; ++p) {
            int f = tid + p * 256;
            int row = f >> 3, c4 = f & 7;
            float4 v = *(const float4*)(X + (long)(n0 + row) * 512 + dc + 4 * c4);
            Xs[row][4*c4+0] = v.x; Xs[row][4*c4+1] = v.y;
            Xs[row][4*c4+2] = v.z; Xs[row][4*c4+3] = v.w;
        }
        __syncthreads();
        for (int d2 = 0; d2 < 32; ++d2) {
            float xv = Xs[tid][d2];
#pragma unroll
            for (int e = 0; e < 8; ++e) acc[e] += xv * W[dc + d2][e];
        }
    }
    float v1 = -3.0e38f; int i1 = 0;
#pragma unroll
    for (int e = 0; e < 8; ++e) if (acc[e] > v1) { v1 = acc[e]; i1 = e; }
    float v2 = -3.0e38f; int i2 = -1;
#pragma unroll
    for (int e = 0; e < 8; ++e) if (e != i1 && acc[e] > v2) { v2 = acc[e]; i2 = e; }
    float t = __expf(v2 - v1);
    float g1 = 1.0f / (1.0f + t);
    float g2 = t / (1.0f + t);
#pragma unroll
    for (int e = 0; e < 8; ++e)
        gates[(long)(n0 + tid) * 8 + e] = (e == i1) ? g1 : ((e == i2) ? g2 : 0.0f);
}

// ---------------------------------------------------------------------------
// combine: gm = sum_e gates[n][e] * eo[e][n][:]  -> split hi/lo f16
// ---------------------------------------------------------------------------
__global__ void __launch_bounds__(256) combine_moe(
    const float* __restrict__ eo, const float* __restrict__ gates,
    _Float16* __restrict__ gh, _Float16* __restrict__ gl)
{
    const int idx = blockIdx.x * 256 + threadIdx.x;
    const int n = idx >> 7;
    const int c = (idx & 127) * 4;
    float g[8];
#pragma unroll
    for (int e = 0; e < 8; ++e) g[e] = gates[(long)n * 8 + e];
    float ax = 0.f, ay = 0.f, az = 0.f, aw = 0.f;
#pragma unroll
    for (int e = 0; e < 8; ++e) {
        if (g[e] != 0.0f) {     // wave-uniform (n uniform within a wave)
            float4 v = *(const float4*)(eo + (long)e * 2097152 + (long)n * 512 + c);
            ax += g[e] * v.x; ay += g[e] * v.y; az += g[e] * v.z; aw += g[e] * v.w;
        }
    }
    half4v h, l;
    h[0] = (_Float16)ax; h[1] = (_Float16)ay; h[2] = (_Float16)az; h[3] = (_Float16)aw;
    l[0] = (_Float16)(ax - (float)h[0]); l[1] = (_Float16)(ay - (float)h[1]);
    l[2] = (_Float16)(az - (float)h[2]); l[3] = (_Float16)(aw - (float)h[3]);
    *(half4v*)(gh + (long)n * 512 + c) = h;
    *(half4v*)(gl + (long)n * 512 + c) = l;
}

// ---------------------------------------------------------------------------
extern "C" void kernel_launch(void* const* d_in, const int* in_sizes, int n_in,
                              void* d_out, int out_size, void* d_ws, size_t ws_size,
                              hipStream_t stream) {
    const float* query     = (const float*)d_in[0];
    const float* key       = (const float*)d_in[1];
    // d_in[2] = value: UNUSED by the reference (V is projected from `key`)
    const float* logit_key = (const float*)d_in[3];
    const unsigned char* mask = (const unsigned char*)d_in[4];
    const float* Wq = (const float*)d_in[5];
    const float* Wk = (const float*)d_in[6];
    const float* Wv = (const float*)d_in[7];
    const float* Wo = (const float*)d_in[8];
    const float* wg = (const float*)d_in[9];
    const float* Ew = (const float*)d_in[10];
    float* out = (float*)d_out;

    // ---- workspace map (bytes) — aliases annotated ----
    char* W = (char*)d_ws;
    float*    Qp    = (float*)(W);                    //  8,388,608  fp32 Qcat
    float*    Kp    = (float*)(W + 8388608);          // 67,108,864  fp32 Kcat  -> after flash: lk split
    float*    Vp    = (float*)(W + 75497472);         // 67,108,864  fp32 Vcat  -> after flash: gm split
    _Float16* k_hi  = (_Float16*)(W + 142606336);     // 33,554,432  key split  -> after proj: eo
    _Float16* k_lo  = (_Float16*)(W + 176160768);     // 33,554,432
    float*    eo    = (float*)(W + 142606336);        // 67,108,864  expert_out (aliases k_hi/k_lo)
    _Float16* lk_hi = (_Float16*)(W + 8388608);       // aliases Kp
    _Float16* lk_lo = (_Float16*)(W + 41943040);
    _Float16* gm_hi = (_Float16*)(W + 75497472);      // aliases Vp
    _Float16* gm_lo = (_Float16*)(W + 79691776);
    _Float16* q_hi  = (_Float16*)(W + 209715200);     //  4,194,304
    _Float16* q_lo  = (_Float16*)(W + 213909504);
    _Float16* wq_hi = (_Float16*)(W + 218103808);     //  524,288 each, 8 arrays
    _Float16* wq_lo = (_Float16*)(W + 218628096);
    _Float16* wk_hi = (_Float16*)(W + 219152384);
    _Float16* wk_lo = (_Float16*)(W + 219676672);
    _Float16* wv_hi = (_Float16*)(W + 220200960);
    _Float16* wv_lo = (_Float16*)(W + 220725248);
    _Float16* wo_hi = (_Float16*)(W + 221249536);
    _Float16* wo_lo = (_Float16*)(W + 221773824);
    _Float16* ew_hi = (_Float16*)(W + 222298112);     //  4,194,304
    _Float16* ew_lo = (_Float16*)(W + 226492416);
    _Float16* hd_hi = (_Float16*)(W + 230686720);     //  4,194,304
    _Float16* hd_lo = (_Float16*)(W + 234881024);
    float*    glim  = (float*)(W + 239075328);        //  8,388,608
    _Float16* gl_hi = (_Float16*)(W + 247463936);     //  4,194,304
    _Float16* gl_lo = (_Float16*)(W + 251658240);
    float*    gates = (float*)(W + 255852544);        //  131,072    total ~256 MB

    dim3 blk(256);

    // ---- input splits / weight packs ----
    split_f16<<<dim3(2048), blk, 0, stream>>>(query, q_hi, q_lo, 524288);
    split_f16<<<dim3(16384), blk, 0, stream>>>(key, k_hi, k_lo, 4194304);
    // Wq/Wk/Wv: [H][D][DK] -> [h*64+k][d]  (batched 512x64 transpose per h)
    transpose_split<<<dim3(2, 16, 8), blk, 0, stream>>>(Wq, wq_hi, wq_lo, 512, 64);
    transpose_split<<<dim3(2, 16, 8), blk, 0, stream>>>(Wk, wk_hi, wk_lo, 512, 64);
    transpose_split<<<dim3(2, 16, 8), blk, 0, stream>>>(Wv, wv_hi, wv_lo, 512, 64);
    // Wo: [H][DK][D] == [512][512] rows n=h*64+k -> Wo_t[d][n]
    transpose_split<<<dim3(16, 16, 1), blk, 0, stream>>>(Wo, wo_hi, wo_lo, 512, 512);
    // Ew: [E][D][O] -> [e][o][d]
    transpose_split<<<dim3(16, 16, 8), blk, 0, stream>>>(Ew, ew_hi, ew_lo, 512, 512);

    // ---- projections (f16x3 MFMA) ----
    gemm_f16x3<<<dim3(4, 32, 1), blk, 0, stream>>>(
        q_hi, q_lo, wq_hi, wq_lo, Qp, nullptr, nullptr, 512, 0, 0, 0, 1.0f);
    gemm_f16x3<<<dim3(4, 256, 1), blk, 0, stream>>>(
        k_hi, k_lo, wk_hi, wk_lo, Kp, nullptr, nullptr, 512, 0, 0, 0, 1.0f);
    gemm_f16x3<<<dim3(4, 256, 1), blk, 0, stream>>>(
        k_hi, k_lo, wv_hi, wv_lo, Vp, nullptr, nullptr, 512, 0, 0, 0, 1.0f);

    // ---- attention (fp32) ----
    flash_attn<<<dim3(4, H_, B_), blk, 0, stream>>>(Qp, Kp, Vp, mask, hd_hi, hd_lo);

    // lk split AFTER flash (aliases Kp)
    split_f16<<<dim3(16384), blk, 0, stream>>>(logit_key, lk_hi, lk_lo, 4194304);

    // ---- Wo merge -> glimpse (fp32 + split) ----
    gemm_f16x3<<<dim3(4, 32, 1), blk, 0, stream>>>(
        hd_hi, hd_lo, wo_hi, wo_lo, glim, gl_hi, gl_lo, 512, 0, 0, 0, 1.0f);

    // ---- gating ----
    gate_topk<<<dim3(16), blk, 0, stream>>>(glim, wg, gates);

    // ---- MoE experts (batched over e) ----
    gemm_f16x3<<<dim3(4, 32, 8), blk, 0, stream>>>(
        gl_hi, gl_lo, ew_hi, ew_lo, eo, nullptr, nullptr, 512, 0, 512, 2097152, 1.0f);

    // ---- gate-weighted combine -> gm split (aliases Vp) ----
    combine_moe<<<dim3(2048), blk, 0, stream>>>(eo, gates, gm_hi, gm_lo);

    // ---- final logits: out[b] = gm[b] @ lk[b]^T / sqrt(512) ----
    gemm_f16x3<<<dim3(16, 2, 16), blk, 0, stream>>>(
        gm_hi, gm_lo, lk_hi, lk_lo, out, nullptr, nullptr, 2048,
        256, 2048, 524288, 0.04419417382415922f);
}

// Round 3
// 609.207 us; speedup vs baseline: 2.2846x; 1.3653x over previous
//
#include <hip/hip_runtime.h>

#define B_  16
#define S_  256
#define G_  2048
#define D_  512
#define H_  8
#define DK_ 64
#define E_  8

typedef _Float16 half8  __attribute__((ext_vector_type(8)));
typedef _Float16 half4v __attribute__((ext_vector_type(4)));
typedef float    floatx4 __attribute__((ext_vector_type(4)));

// async global->LDS, 16B per lane; LDS dest = wave-uniform base + lane*16
#define GLDS(g, l) __builtin_amdgcn_global_load_lds( \
    (const __attribute__((address_space(1))) void*)(g), \
    (__attribute__((address_space(3))) void*)(l), 16, 0, 0)

// ---------------------------------------------------------------------------
// split fp32 -> hi/lo f16 (x = hi + lo, residual ~2^-22 rel)
// ---------------------------------------------------------------------------
__global__ void __launch_bounds__(256) split_f16(
    const float* __restrict__ src, _Float16* __restrict__ hi,
    _Float16* __restrict__ lo, int n4)
{
    int i = blockIdx.x * 256 + threadIdx.x;
    if (i >= n4) return;
    float4 v = ((const float4*)src)[i];
    half4v h, l;
    h[0] = (_Float16)v.x; h[1] = (_Float16)v.y;
    h[2] = (_Float16)v.z; h[3] = (_Float16)v.w;
    l[0] = (_Float16)(v.x - (float)h[0]); l[1] = (_Float16)(v.y - (float)h[1]);
    l[2] = (_Float16)(v.z - (float)h[2]); l[3] = (_Float16)(v.w - (float)h[3]);
    ((half4v*)hi)[i] = h;
    ((half4v*)lo)[i] = l;
}

// ---------------------------------------------------------------------------
// transpose + split: dst[c][r] = src[z][r][c], dst ld = R. (weights pack)
// grid: (C/32, R/32, Z)
// ---------------------------------------------------------------------------
__global__ void __launch_bounds__(256) transpose_split(
    const float* __restrict__ src, _Float16* __restrict__ hi,
    _Float16* __restrict__ lo, int R, int C)
{
    __shared__ float T[32][33];
    const int tid = threadIdx.x;
    const long zo = (long)blockIdx.z * R * C;
    const int r0 = blockIdx.y * 32, c0 = blockIdx.x * 32;
#pragma unroll
    for (int p = 0; p < 4; ++p) {
        int i = tid + p * 256;
        int lr = i >> 5, lc = i & 31;
        T[lr][lc] = src[zo + (long)(r0 + lr) * C + (c0 + lc)];
    }
    __syncthreads();
#pragma unroll
    for (int p = 0; p < 4; ++p) {
        int i = tid + p * 256;
        int orr = i >> 5, oc = i & 31;
        float v = T[oc][orr];
        _Float16 h = (_Float16)v;
        long o = zo + (long)(c0 + orr) * R + (r0 + oc);
        hi[o] = h;
        lo[o] = (_Float16)(v - (float)h);
    }
}

// ---------------------------------------------------------------------------
// f16x3 MFMA GEMM (NT): C = alpha * (Ah+Al)(M x 512) @ (Bh+Bl)(N x 512)^T
// 128x128 tile, 4 waves (64x64 each, 4x4 of 16x16x32 MFMA), BK=32.
// A,B k-major ld=512. C (fp32) nullable; split output (Chi/Clo) nullable.
// z: A rows += z*sAz, B rows += z*sBz, C += z*sCz.
// ---------------------------------------------------------------------------
__global__ void __launch_bounds__(256) gemm_f16x3(
    const _Float16* __restrict__ Ah, const _Float16* __restrict__ Al,
    const _Float16* __restrict__ Bh, const _Float16* __restrict__ Bl,
    float* __restrict__ C, _Float16* __restrict__ Chi, _Float16* __restrict__ Clo,
    long ldc, long sAz, long sBz, long sCz, float alpha)
{
    __shared__ _Float16 Ash[128 * 32], Asl[128 * 32];
    __shared__ _Float16 Bsh[128 * 32], Bsl[128 * 32];
    const int tid = threadIdx.x;
    const int w = tid >> 6, lane = tid & 63;
    const int quad = lane >> 4, tn = lane & 15;
    const int wm = (w >> 1) * 64, wn = (w & 1) * 64;
    const int z = blockIdx.z;
    const long m0 = (long)blockIdx.y * 128;
    const long n0 = (long)blockIdx.x * 128;
    const _Float16* Agh = Ah + (z * sAz + m0) * 512;
    const _Float16* Agl = Al + (z * sAz + m0) * 512;
    const _Float16* Bgh = Bh + (z * sBz + n0) * 512;
    const _Float16* Bgl = Bl + (z * sBz + n0) * 512;
    const long glane = (long)(lane >> 2) * 512 + (lane & 3) * 8;

    floatx4 acc[4][4] = {};

    for (int k0 = 0; k0 < 512; k0 += 32) {
#pragma unroll
        for (int cc = 0; cc < 2; ++cc) {           // each wave stages 2 of 8 chunks
            const int c = 2 * w + cc;
            const long go = (long)c * 16 * 512 + glane + k0;
            GLDS(Agh + go, Ash + c * 512);
            GLDS(Agl + go, Asl + c * 512);
            GLDS(Bgh + go, Bsh + c * 512);
            GLDS(Bgl + go, Bsl + c * 512);
        }
        asm volatile("s_waitcnt vmcnt(0)" ::: "memory");
        __syncthreads();

        half8 ah[4], al[4], bh[4], bl[4];
#pragma unroll
        for (int t = 0; t < 4; ++t) {
            ah[t] = *(const half8*)&Ash[(wm + t * 16 + tn) * 32 + quad * 8];
            al[t] = *(const half8*)&Asl[(wm + t * 16 + tn) * 32 + quad * 8];
            bh[t] = *(const half8*)&Bsh[(wn + t * 16 + tn) * 32 + quad * 8];
            bl[t] = *(const half8*)&Bsl[(wn + t * 16 + tn) * 32 + quad * 8];
        }
#pragma unroll
        for (int i = 0; i < 4; ++i)
#pragma unroll
            for (int j = 0; j < 4; ++j) {
                acc[i][j] = __builtin_amdgcn_mfma_f32_16x16x32_f16(ah[i], bh[j], acc[i][j], 0, 0, 0);
                acc[i][j] = __builtin_amdgcn_mfma_f32_16x16x32_f16(ah[i], bl[j], acc[i][j], 0, 0, 0);
                acc[i][j] = __builtin_amdgcn_mfma_f32_16x16x32_f16(al[i], bh[j], acc[i][j], 0, 0, 0);
            }
        __syncthreads();
    }

#pragma unroll
    for (int i = 0; i < 4; ++i) {
        const long row0 = m0 + wm + i * 16 + quad * 4;
#pragma unroll
        for (int r = 0; r < 4; ++r) {
            const long row = row0 + r;
#pragma unroll
            for (int j = 0; j < 4; ++j) {
                float v = acc[i][j][r] * alpha;
                const long o = (long)z * sCz + row * ldc + n0 + wn + j * 16 + tn;
                if (C) C[o] = v;
                if (Chi) {
                    _Float16 hh = (_Float16)v;
                    Chi[o] = hh;
                    Clo[o] = (_Float16)(v - (float)hh);
                }
            }
        }
    }
}

// ---------------------------------------------------------------------------
// MFMA flash attention, f16x3, no-max softmax (scores bounded; log2e/sqrt(DK)
// pre-folded into Q). 512 thr = 8 waves; wave owns 16 s-rows; block = 128 s.
// K: [token][512] hi/lo f16 (projected).  V: TRANSPOSED [dkcol 512][token] hi/lo.
// LDS XOR-swizzle (granule16 ^ row) keeps fragment reads <=2-way conflicts.
// ---------------------------------------------------------------------------
__global__ void __launch_bounds__(512) flash_mfma(
    const _Float16* __restrict__ qh, const _Float16* __restrict__ qlo,
    const _Float16* __restrict__ kh, const _Float16* __restrict__ kl,
    const _Float16* __restrict__ vh, const _Float16* __restrict__ vl,
    const unsigned char* __restrict__ mask,
    _Float16* __restrict__ hd_hi, _Float16* __restrict__ hd_lo)
{
    __shared__ half8 KH[512], KL[512], VH[512], VL[512];   // 64 rows x 8 gran, swizzled
    __shared__ float PLb[8 * 16 * 64];                     // per-wave P (f32, swizzled)
    const int tid = threadIdx.x;
    const int wid = tid >> 6, lane = tid & 63;
    const int quad = lane >> 4, tn = lane & 15;
    const int h = blockIdx.y, b = blockIdx.z;
    const int s_base = blockIdx.x * 128 + wid * 16;
    const long tok0 = (long)b * S_ + s_base;
    float* Pw = PLb + wid * (16 * 64);
    const unsigned char* mb = mask + (long)b * G_;

    // Q fragments (A-layout: row = tn, k = k0*32 + quad*8), loaded once
    const long qoff = (tok0 + tn) * 512 + h * 64 + quad * 8;
    half8 qfh[2], qfl[2];
    qfh[0] = *(const half8*)(qh + qoff);
    qfh[1] = *(const half8*)(qh + qoff + 32);
    qfl[0] = *(const half8*)(qlo + qoff);
    qfl[1] = *(const half8*)(qlo + qoff + 32);

    // staging role: 512 threads cover 64 rows x 8 granules(16B)
    const int sr = tid >> 3, sg = tid & 7;
    const int swz = sr * 8 + (sg ^ (sr & 7));
    const long kgbase = (long)b * G_ * 512 + h * 64 + sg * 8;           // +(g0+sr)*512
    const long vgbase = (long)(h * 64 + sr) * (B_ * G_) + (long)b * G_ + sg * 8;  // +g0

    half8 pk0 = *(const half8*)(kh + kgbase + (long)sr * 512);
    half8 pk1 = *(const half8*)(kl + kgbase + (long)sr * 512);
    half8 pk2 = *(const half8*)(vh + vgbase);
    half8 pk3 = *(const half8*)(vl + vgbase);

    floatx4 accO[4] = {};
    float lsum[4] = {0.f, 0.f, 0.f, 0.f};

    for (int t = 0; t < 32; ++t) {
        KH[swz] = pk0; KL[swz] = pk1; VH[swz] = pk2; VL[swz] = pk3;
        __syncthreads();
        if (t < 31) {                       // prefetch next tile (overlaps compute)
            const int g1 = (t + 1) * 64;
            pk0 = *(const half8*)(kh + kgbase + (long)(g1 + sr) * 512);
            pk1 = *(const half8*)(kl + kgbase + (long)(g1 + sr) * 512);
            pk2 = *(const half8*)(vh + vgbase + g1);
            pk3 = *(const half8*)(vl + vgbase + g1);
        }
        const int g0 = t * 64;

        // ---- scores = Q K^T (pre-scaled to log2 units) ----
        floatx4 accS[4] = {};
#pragma unroll
        for (int k0 = 0; k0 < 2; ++k0)
#pragma unroll
            for (int nj = 0; nj < 4; ++nj) {
                const int row = nj * 16 + tn;
                const int gi = row * 8 + ((k0 * 4 + quad) ^ (row & 7));
                half8 kbh = KH[gi], kbl = KL[gi];
                accS[nj] = __builtin_amdgcn_mfma_f32_16x16x32_f16(qfh[k0], kbh, accS[nj], 0, 0, 0);
                accS[nj] = __builtin_amdgcn_mfma_f32_16x16x32_f16(qfh[k0], kbl, accS[nj], 0, 0, 0);
                accS[nj] = __builtin_amdgcn_mfma_f32_16x16x32_f16(qfl[k0], kbh, accS[nj], 0, 0, 0);
            }

        // ---- exp2 + mask + row-sums (C-layout: row=quad*4+rr, col=tn) ----
        float rs[4] = {0.f, 0.f, 0.f, 0.f};
#pragma unroll
        for (int nj = 0; nj < 4; ++nj) {
            const bool mk = mb[g0 + nj * 16 + tn] != 0;
#pragma unroll
            for (int rr = 0; rr < 4; ++rr) {
                float p = __builtin_exp2f(accS[nj][rr]);
                p = mk ? 0.0f : p;
                accS[nj][rr] = p;
                rs[rr] += p;
            }
        }
#pragma unroll
        for (int rr = 0; rr < 4; ++rr) {
            float v = rs[rr];
            v += __shfl_xor(v, 1); v += __shfl_xor(v, 2);
            v += __shfl_xor(v, 4); v += __shfl_xor(v, 8);
            lsum[rr] += v;
        }

        // ---- P -> own LDS region (f32, swizzled granule16 ^ srow) ----
#pragma unroll
        for (int nj = 0; nj < 4; ++nj)
#pragma unroll
            for (int rr = 0; rr < 4; ++rr) {
                const int srow = quad * 4 + rr;
                const int c = nj * 16 + tn;
                Pw[srow * 64 + ((((c >> 2) ^ srow) & 15) << 2) + (c & 3)] = accS[nj][rr];
            }
        asm volatile("s_waitcnt lgkmcnt(0)" ::: "memory");

        // ---- O += P V (A-frag from LDS f32, split hi/lo via mantissa-AND) ----
#pragma unroll
        for (int k0 = 0; k0 < 2; ++k0) {
            const int ga = k0 * 8 + quad * 2;
            floatx4 p0 = *(floatx4*)&Pw[tn * 64 + (((ga ^ tn) & 15) << 2)];
            floatx4 p1 = *(floatx4*)&Pw[tn * 64 + ((((ga + 1) ^ tn) & 15) << 2)];
            half8 ph, pl;
#pragma unroll
            for (int e = 0; e < 8; ++e) {
                const float x = (e < 4) ? p0[e & 3] : p1[e & 3];
                const float hi = __uint_as_float(__float_as_uint(x) & 0xFFFFE000u);
                ph[e] = (_Float16)hi;
                pl[e] = (_Float16)(x - hi);
            }
#pragma unroll
            for (int nj = 0; nj < 4; ++nj) {
                const int row = nj * 16 + tn;
                const int gi = row * 8 + ((k0 * 4 + quad) ^ (row & 7));
                half8 vbh = VH[gi], vbl = VL[gi];
                accO[nj] = __builtin_amdgcn_mfma_f32_16x16x32_f16(ph, vbh, accO[nj], 0, 0, 0);
                accO[nj] = __builtin_amdgcn_mfma_f32_16x16x32_f16(ph, vbl, accO[nj], 0, 0, 0);
                accO[nj] = __builtin_amdgcn_mfma_f32_16x16x32_f16(pl, vbh, accO[nj], 0, 0, 0);
            }
        }
        __syncthreads();
    }

    // ---- epilogue: O/l, split hi/lo, write heads [token][h*64+dk] ----
#pragma unroll
    for (int rr = 0; rr < 4; ++rr) {
        const float inv = 1.0f / lsum[rr];
        const long rbase = (tok0 + quad * 4 + rr) * 512 + h * 64 + tn;
#pragma unroll
        for (int nj = 0; nj < 4; ++nj) {
            const float o = accO[nj][rr] * inv;
            const _Float16 oh = (_Float16)o;
            hd_hi[rbase + nj * 16] = oh;
            hd_lo[rbase + nj * 16] = (_Float16)(o - (float)oh);
        }
    }
}

// ---------------------------------------------------------------------------
// Gate: logits = glimpse @ w_gate (glimpse as hi/lo f16), top-2, softmax
// ---------------------------------------------------------------------------
__global__ void __launch_bounds__(256) gate_topk(
    const _Float16* __restrict__ Xh, const _Float16* __restrict__ Xl,
    const float* __restrict__ wg, float* __restrict__ gates)
{
    __shared__ float W[512][8];
    __shared__ float Xs[256][37];
    const int tid = threadIdx.x;
    const int n0 = blockIdx.x * 256;
#pragma unroll
    for (int p = 0; p < 16; ++p) ((float*)W)[tid + p * 256] = wg[tid + p * 256];

    float acc[8] = {};
    for (int dc = 0; dc < 512; dc += 32) {
        __syncthreads();
#pragma unroll
        for (int p = 0; p < 8; ++p) {
            int f = tid + p * 256;
            int row = f >> 3, c4 = f & 7;
            long o = (long)(n0 + row) * 512 + dc + 4 * c4;
            half4v hv = *(const half4v*)(Xh + o);
            half4v lv = *(const half4v*)(Xl + o);
#pragma unroll
            for (int i = 0; i < 4; ++i) Xs[row][4 * c4 + i] = (float)hv[i] + (float)lv[i];
        }
        __syncthreads();
        for (int d2 = 0; d2 < 32; ++d2) {
            float xv = Xs[tid][d2];
#pragma unroll
            for (int e = 0; e < 8; ++e) acc[e] += xv * W[dc + d2][e];
        }
    }
    float v1 = -3.0e38f; int i1 = 0;
#pragma unroll
    for (int e = 0; e < 8; ++e) if (acc[e] > v1) { v1 = acc[e]; i1 = e; }
    float v2 = -3.0e38f; int i2 = -1;
#pragma unroll
    for (int e = 0; e < 8; ++e) if (e != i1 && acc[e] > v2) { v2 = acc[e]; i2 = e; }
    float t = __expf(v2 - v1);
    float g1 = 1.0f / (1.0f + t);
    float g2 = t / (1.0f + t);
#pragma unroll
    for (int e = 0; e < 8; ++e)
        gates[(long)(n0 + tid) * 8 + e] = (e == i1) ? g1 : ((e == i2) ? g2 : 0.0f);
}

// ---------------------------------------------------------------------------
// combine: gm = sum_e gates[n][e] * eo[e][n][:]  -> split hi/lo f16
// ---------------------------------------------------------------------------
__global__ void __launch_bounds__(256) combine_moe(
    const float* __restrict__ eo, const float* __restrict__ gates,
    _Float16* __restrict__ gh, _Float16* __restrict__ gl)
{
    const int idx = blockIdx.x * 256 + threadIdx.x;
    const int n = idx >> 7;
    const int c = (idx & 127) * 4;
    float g[8];
#pragma unroll
    for (int e = 0; e < 8; ++e) g[e] = gates[(long)n * 8 + e];
    float ax = 0.f, ay = 0.f, az = 0.f, aw = 0.f;
#pragma unroll
    for (int e = 0; e < 8; ++e) {
        if (g[e] != 0.0f) {
            float4 v = *(const float4*)(eo + (long)e * 2097152 + (long)n * 512 + c);
            ax += g[e] * v.x; ay += g[e] * v.y; az += g[e] * v.z; aw += g[e] * v.w;
        }
    }
    half4v h, l;
    h[0] = (_Float16)ax; h[1] = (_Float16)ay; h[2] = (_Float16)az; h[3] = (_Float16)aw;
    l[0] = (_Float16)(ax - (float)h[0]); l[1] = (_Float16)(ay - (float)h[1]);
    l[2] = (_Float16)(az - (float)h[2]); l[3] = (_Float16)(aw - (float)h[3]);
    *(half4v*)(gh + (long)n * 512 + c) = h;
    *(half4v*)(gl + (long)n * 512 + c) = l;
}

// ---------------------------------------------------------------------------
extern "C" void kernel_launch(void* const* d_in, const int* in_sizes, int n_in,
                              void* d_out, int out_size, void* d_ws, size_t ws_size,
                              hipStream_t stream) {
    const float* query     = (const float*)d_in[0];
    const float* key       = (const float*)d_in[1];
    // d_in[2] = value: UNUSED by the reference (V is projected from `key`)
    const float* logit_key = (const float*)d_in[3];
    const unsigned char* mask = (const unsigned char*)d_in[4];
    const float* Wq = (const float*)d_in[5];
    const float* Wk = (const float*)d_in[6];
    const float* Wv = (const float*)d_in[7];
    const float* Wo = (const float*)d_in[8];
    const float* wg = (const float*)d_in[9];
    const float* Ew = (const float*)d_in[10];
    float* out = (float*)d_out;

    // ---- workspace map (1 MB = 1048576 B); aliases annotated ----
    const size_t MBy = 1048576;
    char* W = (char*)d_ws;
    _Float16* q_hi  = (_Float16*)(W + 0 * MBy);    // projected Q (scaled), 4 MB each
    _Float16* q_lo  = (_Float16*)(W + 4 * MBy);
    _Float16* kp_hi = (_Float16*)(W + 8 * MBy);    // projected K, 32 MB each
    _Float16* kp_lo = (_Float16*)(W + 40 * MBy);
    _Float16* vt_hi = (_Float16*)(W + 72 * MBy);   // projected V^T [512][32768]
    _Float16* vt_lo = (_Float16*)(W + 104 * MBy);
    _Float16* kin_hi = (_Float16*)(W + 136 * MBy); // key split (dead after VT-proj)
    _Float16* kin_lo = (_Float16*)(W + 168 * MBy);
    float*    eo    = (float*)(W + 136 * MBy);     // expert_out 67MB (alias, after)
    _Float16* lk_hi = (_Float16*)(W + 136 * MBy);  // logit_key split (after combine)
    _Float16* lk_lo = (_Float16*)(W + 168 * MBy);
    _Float16* wq_hi = (_Float16*)(W + 204 * MBy);
    _Float16* wq_lo = (_Float16*)(W + 204 * MBy + 524288);
    _Float16* wk_hi = (_Float16*)(W + 205 * MBy);
    _Float16* wk_lo = (_Float16*)(W + 205 * MBy + 524288);
    _Float16* wv_hi = (_Float16*)(W + 206 * MBy);
    _Float16* wv_lo = (_Float16*)(W + 206 * MBy + 524288);
    _Float16* wo_hi = (_Float16*)(W + 207 * MBy);
    _Float16* wo_lo = (_Float16*)(W + 207 * MBy + 524288);
    _Float16* ew_hi = (_Float16*)(W + 208 * MBy);
    _Float16* ew_lo = (_Float16*)(W + 212 * MBy);
    _Float16* qi_hi = (_Float16*)(W + 216 * MBy);  // query split (dead after Q-proj)
    _Float16* qi_lo = (_Float16*)(W + 220 * MBy);
    _Float16* hd_hi = (_Float16*)(W + 216 * MBy);  // heads (alias qi, after)
    _Float16* hd_lo = (_Float16*)(W + 220 * MBy);
    _Float16* gl_hi = (_Float16*)(W + 224 * MBy);  // glimpse
    _Float16* gl_lo = (_Float16*)(W + 228 * MBy);
    _Float16* gm_hi = (_Float16*)(W + 232 * MBy);  // moe output
    _Float16* gm_lo = (_Float16*)(W + 236 * MBy);
    float*    gates = (float*)(W + 240 * MBy);     // 128 KB; top ~240.1 MB

    dim3 blk(256);

    // ---- input splits / weight packs ----
    split_f16<<<dim3(16384), blk, 0, stream>>>(key, kin_hi, kin_lo, 4194304);
    split_f16<<<dim3(2048), blk, 0, stream>>>(query, qi_hi, qi_lo, 524288);
    transpose_split<<<dim3(2, 16, 8), blk, 0, stream>>>(Wq, wq_hi, wq_lo, 512, 64);
    transpose_split<<<dim3(2, 16, 8), blk, 0, stream>>>(Wk, wk_hi, wk_lo, 512, 64);
    transpose_split<<<dim3(2, 16, 8), blk, 0, stream>>>(Wv, wv_hi, wv_lo, 512, 64);
    transpose_split<<<dim3(16, 16, 1), blk, 0, stream>>>(Wo, wo_hi, wo_lo, 512, 512);
    transpose_split<<<dim3(16, 16, 8), blk, 0, stream>>>(Ew, ew_hi, ew_lo, 512, 512);

    // ---- projections (f16x3 MFMA, f16 hi/lo outputs only) ----
    // Q scaled by log2e/sqrt(DK) so flash uses exp2 with no per-score multiply
    gemm_f16x3<<<dim3(4, 32, 1), blk, 0, stream>>>(
        qi_hi, qi_lo, wq_hi, wq_lo, nullptr, q_hi, q_lo, 512, 0, 0, 0,
        0.1803368801111204f);
    gemm_f16x3<<<dim3(4, 256, 1), blk, 0, stream>>>(
        kin_hi, kin_lo, wk_hi, wk_lo, nullptr, kp_hi, kp_lo, 512, 0, 0, 0, 1.0f);
    // V^T = Wv^T @ key^T : A = wv pack (512x512 k-major), B = key split
    gemm_f16x3<<<dim3(256, 4, 1), blk, 0, stream>>>(
        wv_hi, wv_lo, kin_hi, kin_lo, nullptr, vt_hi, vt_lo, (long)B_ * G_,
        0, 0, 0, 1.0f);

    // ---- attention (MFMA f16x3, no-max online-sum softmax) ----
    flash_mfma<<<dim3(2, H_, B_), dim3(512), 0, stream>>>(
        q_hi, q_lo, kp_hi, kp_lo, vt_hi, vt_lo, mask, hd_hi, hd_lo);

    // ---- Wo merge -> glimpse (hi/lo) ----
    gemm_f16x3<<<dim3(4, 32, 1), blk, 0, stream>>>(
        hd_hi, hd_lo, wo_hi, wo_lo, nullptr, gl_hi, gl_lo, 512, 0, 0, 0, 1.0f);

    // ---- gating ----
    gate_topk<<<dim3(16), blk, 0, stream>>>(gl_hi, gl_lo, wg, gates);

    // ---- MoE experts (dense over e; gates re-zero non-top2) ----
    gemm_f16x3<<<dim3(4, 32, 8), blk, 0, stream>>>(
        gl_hi, gl_lo, ew_hi, ew_lo, eo, nullptr, nullptr, 512, 0, 512, 2097152, 1.0f);

    // ---- gate-weighted combine -> gm (hi/lo) ----
    combine_moe<<<dim3(2048), blk, 0, stream>>>(eo, gates, gm_hi, gm_lo);

    // ---- logit_key split (after eo consumed; aliases its region) ----
    split_f16<<<dim3(16384), blk, 0, stream>>>(logit_key, lk_hi, lk_lo, 4194304);

    // ---- final logits: out[b] = gm[b] @ lk[b]^T / sqrt(512) ----
    gemm_f16x3<<<dim3(16, 2, 16), blk, 0, stream>>>(
        gm_hi, gm_lo, lk_hi, lk_lo, out, nullptr, nullptr, 2048,
        256, 2048, 524288, 0.04419417382415922f);
}